// Round 1
// baseline (1350.016 us; speedup 1.0000x reference)
//
#include <hip/hip_runtime.h>

#define NN 4096
#define RR 16
#define BB 8
#define DIN 64
#define DOUT 32
#define KTOT (RR * NN)   // 65536

typedef float f32x4_t __attribute__((ext_vector_type(4)));
typedef short bf16x8_t __attribute__((ext_vector_type(8)));
typedef short bf16x4_t __attribute__((ext_vector_type(4)));

__device__ __forceinline__ short f2bf(float f) {
    unsigned u = __float_as_uint(f);
    u += 0x7FFFu + ((u >> 16) & 1u);   // RNE
    return (short)(u >> 16);
}

__device__ __forceinline__ bf16x8_t cvt8(float4 x, float4 y) {
    bf16x8_t r;
    r[0] = f2bf(x.x); r[1] = f2bf(x.y); r[2] = f2bf(x.z); r[3] = f2bf(x.w);
    r[4] = f2bf(y.x); r[5] = f2bf(y.y); r[6] = f2bf(y.z); r[7] = f2bf(y.w);
    return r;
}

// WT[r][c][j] = sum_b comp[r,b] * W_F[b][j][c]   (bf16, B-operand-friendly)
__global__ void k_weights(const float* __restrict__ WF,
                          const float* __restrict__ comp,
                          short* __restrict__ WT) {
    int t = blockIdx.x * 256 + threadIdx.x;       // 32768 = 16*32*64
    int r = t >> 11;
    int c = (t >> 6) & 31;
    int j = t & 63;
    float s = 0.f;
#pragma unroll
    for (int b = 0; b < BB; ++b)
        s += comp[r * BB + b] * WF[b * (DIN * DOUT) + j * DOUT + c];
    WT[t] = f2bf(s);   // flat index == r*2048 + c*64 + j
}

// FWT[c][r*4096+n] = sum_j X[n,j] * W[r][j][c]   via 16x16x32 bf16 MFMA
__global__ __launch_bounds__(256) void k_fwt(const float* __restrict__ X,
                                             const short* __restrict__ WT,
                                             short* __restrict__ FWT) {
    int w = threadIdx.x >> 6;
    int l = threadIdx.x & 63;
    int lrow = l & 15, quad = l >> 4;
    int r = blockIdx.x >> 6;
    int n0 = ((blockIdx.x & 63) * 4 + w) * 16;

    const char* Xb = (const char*)X;
    const char* Wb = (const char*)(WT + r * (32 * 64));
    unsigned offA  = ((unsigned)(n0 + lrow) * DIN + quad * 8u) * 4u;
    unsigned offB0 = ((unsigned)lrow * DIN + quad * 8u) * 2u;
    unsigned offB1 = offB0 + 16u * DIN * 2u;

    f32x4_t acc0 = {0.f, 0.f, 0.f, 0.f}, acc1 = {0.f, 0.f, 0.f, 0.f};
#pragma unroll
    for (int s = 0; s < 2; ++s) {   // K = 64 = 2 steps of 32
        float4 a0 = *(const float4*)(Xb + offA + s * 128);
        float4 a1 = *(const float4*)(Xb + offA + s * 128 + 16);
        bf16x8_t af = cvt8(a0, a1);
        bf16x8_t b0 = *(const bf16x8_t*)(Wb + offB0 + s * 64);
        bf16x8_t b1 = *(const bf16x8_t*)(Wb + offB1 + s * 64);
        acc0 = __builtin_amdgcn_mfma_f32_16x16x32_bf16(af, b0, acc0, 0, 0, 0);
        acc1 = __builtin_amdgcn_mfma_f32_16x16x32_bf16(af, b1, acc1, 0, 0, 0);
    }
#pragma unroll
    for (int nt = 0; nt < 2; ++nt) {
        f32x4_t a = nt ? acc1 : acc0;
        bf16x4_t sv;
        sv[0] = f2bf(a[0]); sv[1] = f2bf(a[1]);
        sv[2] = f2bf(a[2]); sv[3] = f2bf(a[3]);
        int c = nt * 16 + lrow;                       // D: col = lane&15
        size_t idx = (size_t)c * KTOT + (unsigned)(r * NN + n0 + quad * 4);
        *(bf16x4_t*)(FWT + idx) = sv;                 // D: row = quad*4+reg
    }
}

// Out += A[4096,65536] @ FW[65536,32]; split-K with fp32 atomics.
// Wave = 32 rows x 32 cols; fragments straight from global, no LDS.
__global__ __launch_bounds__(256, 4) void k_main(const float* __restrict__ A,
                                                 const short* __restrict__ FWT,
                                                 float* __restrict__ out) {
    int w = threadIdx.x >> 6;
    int l = threadIdx.x & 63;
    int lrow = l & 15, quad = l >> 4;
    int m0 = blockIdx.x * 128 + w * 32;
    unsigned kbase = blockIdx.y * 2048u;

    const char* Ab = (const char*)A;
    const char* Bb = (const char*)FWT;
    unsigned offA0 = ((unsigned)(m0 + lrow) * KTOT + kbase + quad * 8u) * 4u;
    unsigned offA1 = offA0 + 16u * KTOT * 4u;
    unsigned offB0 = ((unsigned)lrow * KTOT + kbase + quad * 8u) * 2u;
    unsigned offB1 = offB0 + 16u * KTOT * 2u;

    f32x4_t acc00 = {0.f,0.f,0.f,0.f}, acc01 = {0.f,0.f,0.f,0.f};
    f32x4_t acc10 = {0.f,0.f,0.f,0.f}, acc11 = {0.f,0.f,0.f,0.f};

    for (int s = 0; s < 64; ++s) {   // 2048 k per block, 32 per step
        float4 a0 = *(const float4*)(Ab + offA0);
        float4 a1 = *(const float4*)(Ab + offA0 + 16);
        float4 a2 = *(const float4*)(Ab + offA1);
        float4 a3 = *(const float4*)(Ab + offA1 + 16);
        bf16x8_t bf0 = *(const bf16x8_t*)(Bb + offB0);
        bf16x8_t bf1 = *(const bf16x8_t*)(Bb + offB1);
        bf16x8_t af0 = cvt8(a0, a1);
        bf16x8_t af1 = cvt8(a2, a3);
        acc00 = __builtin_amdgcn_mfma_f32_16x16x32_bf16(af0, bf0, acc00, 0, 0, 0);
        acc01 = __builtin_amdgcn_mfma_f32_16x16x32_bf16(af0, bf1, acc01, 0, 0, 0);
        acc10 = __builtin_amdgcn_mfma_f32_16x16x32_bf16(af1, bf0, acc10, 0, 0, 0);
        acc11 = __builtin_amdgcn_mfma_f32_16x16x32_bf16(af1, bf1, acc11, 0, 0, 0);
        offA0 += 128; offA1 += 128; offB0 += 64; offB1 += 64;
    }

#pragma unroll
    for (int mt = 0; mt < 2; ++mt) {
#pragma unroll
        for (int nt = 0; nt < 2; ++nt) {
            f32x4_t a = (mt == 0) ? (nt == 0 ? acc00 : acc01)
                                  : (nt == 0 ? acc10 : acc11);
            int row = m0 + mt * 16 + quad * 4;
            int col = nt * 16 + lrow;
#pragma unroll
            for (int q = 0; q < 4; ++q)
                atomicAdd(&out[(row + q) * DOUT + col], a[q]);
        }
    }
}

extern "C" void kernel_launch(void* const* d_in, const int* in_sizes, int n_in,
                              void* d_out, int out_size, void* d_ws, size_t ws_size,
                              hipStream_t stream) {
    const float* X    = (const float*)d_in[0];
    const float* A    = (const float*)d_in[1];
    const float* WF   = (const float*)d_in[2];
    const float* comp = (const float*)d_in[3];
    float* out = (float*)d_out;

    short* WT  = (short*)d_ws;            // 16*32*64 bf16 = 64 KB
    short* FWT = (short*)d_ws + 32768;    // 32*65536 bf16 = 4 MB

    hipMemsetAsync(d_out, 0, (size_t)NN * DOUT * sizeof(float), stream);
    k_weights<<<dim3(128), dim3(256), 0, stream>>>(WF, comp, WT);
    k_fwt<<<dim3(1024), dim3(256), 0, stream>>>(X, WT, FWT);
    k_main<<<dim3(32, 32), dim3(256), 0, stream>>>(A, FWT, out);
}